// Round 1
// baseline (899.953 us; speedup 1.0000x reference)
//
#include <hip/hip_runtime.h>

#define N_ROWS 400000
#define DIM 256
#define NCLS 1000
#define NCHUNK 32                     // row chunks for segsum
#define NGRP 8                        // column groups of 32
#define ROWS_PER_CHUNK (N_ROWS / NCHUNK)   // 12500
#define NSQ 10                        // matrix squarings -> G^(2^10)

// ---- workspace layout (bytes) ----
#define OFF_PARTIAL 0                        // [NCHUNK*NGRP][NCLS][32] f32 = 32,768,000
#define OFF_NC      32768000                 // [NCLS][DIM] f32 = 1,024,000
#define OFF_MA      33792000                 // 256KB
#define OFF_MB      34054144                 // 256KB
#define OFF_COUNTS  34316288                 // 1000 u32 (zeroed)
#define OFF_COLSUM  34320384                 // 256 f32 (zeroed)
#define OFF_MAXBUF  34321408                 // 16 u32 (zeroed)
#define OFF_ZERO    OFF_COUNTS
#define ZERO_BYTES  (4096 + 1024 + 64)
#define OFF_V0      34321472
#define OFF_Y1      34322496
#define OFF_Y2      34323520
#define OFF_V       34324544

// ---------- pass 1: per-class partial sums (LDS-bucketed, 32-col slice) ----------
__global__ __launch_bounds__(512) void k_segsum(const float* __restrict__ grads,
                                                const int* __restrict__ labels,
                                                float* __restrict__ partial) {
  extern __shared__ float acc[];            // [NCLS][33] padded: bank = (lbl + c) % 32
  const int t = threadIdx.x;
  const int g = blockIdx.x & 7;             // column group (32 cols)
  const int chunk = blockIdx.x >> 3;        // row chunk
  for (int i = t; i < NCLS * 33; i += 512) acc[i] = 0.0f;
  __syncthreads();

  const int c4 = (t & 7) * 4;               // col within group
  const int r0 = chunk * ROWS_PER_CHUNK;
  const float4* g4 = (const float4*)grads;  // 64 float4 per row
  for (int r = r0 + (t >> 3); r < r0 + ROWS_PER_CHUNK; r += 64) {
    int lbl = labels[r];
    float4 v = g4[(size_t)r * 64 + g * 8 + (t & 7)];
    float* a = &acc[lbl * 33 + c4];
    atomicAdd(a + 0, v.x);
    atomicAdd(a + 1, v.y);
    atomicAdd(a + 2, v.z);
    atomicAdd(a + 3, v.w);
  }
  __syncthreads();
  float* dst = partial + (size_t)blockIdx.x * (NCLS * 32);
  for (int e = t; e < NCLS * 32; e += 512)
    dst[e] = acc[(e >> 5) * 33 + (e & 31)];
}

// ---------- label counts ----------
__global__ __launch_bounds__(256) void k_counts(const int* __restrict__ labels,
                                                unsigned* __restrict__ counts) {
  __shared__ unsigned c[NCLS];
  int t = threadIdx.x;
  for (int i = t; i < NCLS; i += 256) c[i] = 0u;
  __syncthreads();
  for (int i = blockIdx.x * 256 + t; i < N_ROWS; i += gridDim.x * 256)
    atomicAdd(&c[labels[i]], 1u);
  __syncthreads();
  for (int i = t; i < NCLS; i += 256) atomicAdd(&counts[i], c[i]);
}

// ---------- reduce partials + EMA update -> new centroids ----------
__global__ __launch_bounds__(256) void k_reduce_ema(const float* __restrict__ partial,
                                                    const unsigned* __restrict__ counts,
                                                    const float* __restrict__ centroids,
                                                    float* __restrict__ NC) {
  int cls = blockIdx.x;
  int d = threadIdx.x;
  int g = d >> 5, c = d & 31;
  float s = 0.0f;
  #pragma unroll
  for (int chunk = 0; chunk < NCHUNK; ++chunk)
    s += partial[(size_t)(chunk * 8 + g) * (NCLS * 32) + cls * 32 + c];
  unsigned cnt = counts[cls];
  float mean = s / fmaxf((float)cnt, 1.0f);
  float ce = centroids[cls * DIM + d];
  NC[cls * DIM + d] = (cnt > 0u) ? (0.9f * ce + 0.1f * mean) : ce;
}

// ---------- column sums of NC (for centering via G = NC'NC - s s'/C) ----------
__global__ __launch_bounds__(256) void k_colsum(const float* __restrict__ NC,
                                                float* __restrict__ colsum) {
  int t = threadIdx.x, b = blockIdx.x;   // 40 blocks x 25 classes
  float s = 0.0f;
  for (int cls = b * 25; cls < b * 25 + 25; ++cls) s += NC[cls * DIM + t];
  atomicAdd(&colsum[t], s);
}

// ---------- Gram of centered centroids + max|.| ----------
__global__ __launch_bounds__(256) void k_gram(const float* __restrict__ NC,
                                              const float* __restrict__ colsum,
                                              float* __restrict__ G,
                                              unsigned* __restrict__ maxb) {
  int j = blockIdx.x, i = threadIdx.x;
  float acc = 0.0f;
  #pragma unroll 4
  for (int k = 0; k < NCLS; ++k)
    acc += NC[k * DIM + i] * NC[k * DIM + j];   // i coalesced, j broadcast
  float val = acc - colsum[i] * colsum[j] * (1.0f / NCLS);
  G[j * DIM + i] = val;
  __shared__ float red[256];
  red[i] = fabsf(val);
  __syncthreads();
  for (int s = 128; s > 0; s >>= 1) {
    if (i < s) red[i] = fmaxf(red[i], red[i + s]);
    __syncthreads();
  }
  if (i == 0) atomicMax(maxb, __float_as_uint(red[0]));
}

// ---------- one normalized squaring step: C = (A/s)^2, track new max ----------
__global__ __launch_bounds__(256) void k_square(const float* __restrict__ A,
                                                float* __restrict__ C,
                                                const unsigned* __restrict__ maxb_in,
                                                unsigned* __restrict__ maxb_out) {
  int j = blockIdx.x, i = threadIdx.x;
  __shared__ float arow[DIM];
  arow[i] = A[j * DIM + i];                 // row j == column j (symmetric)
  __syncthreads();
  float inv = 1.0f / __uint_as_float(*maxb_in);
  float acc = 0.0f;
  #pragma unroll 8
  for (int k = 0; k < DIM; ++k)
    acc += A[k * DIM + i] * arow[k];
  float val = acc * inv * inv;
  C[j * DIM + i] = val;
  __shared__ float red[256];
  red[i] = fabsf(val);
  __syncthreads();
  for (int s = 128; s > 0; s >>= 1) {
    if (i < s) red[i] = fmaxf(red[i], red[i + s]);
    __syncthreads();
  }
  if (i == 0) atomicMax(maxb_out, __float_as_uint(red[0]));
}

// ---------- extract max-norm column of (near rank-1) M ----------
__global__ __launch_bounds__(256) void k_pickcol(const float* __restrict__ M,
                                                 float* __restrict__ v0) {
  int t = threadIdx.x;
  float ns = 0.0f;
  for (int k = 0; k < DIM; ++k) {
    float x = M[k * DIM + t];
    ns += x * x;
  }
  __shared__ float val[256];
  __shared__ int idx[256];
  val[t] = ns; idx[t] = t;
  __syncthreads();
  for (int s = 128; s > 0; s >>= 1) {
    if (t < s && val[t + s] > val[t]) { val[t] = val[t + s]; idx[t] = idx[t + s]; }
    __syncthreads();
  }
  int jm = idx[0];
  float nrm = sqrtf(fmaxf(val[0], 1e-30f));
  v0[t] = M[jm * DIM + t] / nrm;            // row jm == column jm (symmetric)
}

// ---------- matvec y = M x (256 blocks, one row each) ----------
__global__ __launch_bounds__(256) void k_matvec(const float* __restrict__ M,
                                                const float* __restrict__ x,
                                                float* __restrict__ y) {
  int j = blockIdx.x, t = threadIdx.x;
  __shared__ float red[256];
  red[t] = M[j * DIM + t] * x[t];
  __syncthreads();
  for (int s = 128; s > 0; s >>= 1) {
    if (t < s) red[t] += red[t + s];
    __syncthreads();
  }
  if (t == 0) y[j] = red[0];
}

// ---------- normalize ----------
__global__ __launch_bounds__(256) void k_normalize(const float* __restrict__ x,
                                                   float* __restrict__ v) {
  int t = threadIdx.x;
  float xv = x[t];
  __shared__ float red[256];
  red[t] = xv * xv;
  __syncthreads();
  for (int s = 128; s > 0; s >>= 1) {
    if (t < s) red[t] += red[t + s];
    __syncthreads();
  }
  v[t] = xv * rsqrtf(fmaxf(red[0], 1e-30f));
}

// ---------- pass 2: out = g - (g.v) v  (one wave per row, float4/lane) ----------
__global__ __launch_bounds__(256) void k_project(const float4* __restrict__ g4,
                                                 const float* __restrict__ v,
                                                 float4* __restrict__ out) {
  int lane = threadIdx.x & 63;
  float4 v4 = ((const float4*)v)[lane];
  int w = (blockIdx.x * 256 + threadIdx.x) >> 6;
  int nW = (gridDim.x * 256) >> 6;
  for (int r = w; r < N_ROWS; r += nW) {
    float4 g = g4[(size_t)r * 64 + lane];
    float d = g.x * v4.x + g.y * v4.y + g.z * v4.z + g.w * v4.w;
    #pragma unroll
    for (int m = 1; m < 64; m <<= 1) d += __shfl_xor(d, m, 64);
    float4 o = make_float4(g.x - d * v4.x, g.y - d * v4.y,
                           g.z - d * v4.z, g.w - d * v4.w);
    out[(size_t)r * 64 + lane] = o;
  }
}

extern "C" void kernel_launch(void* const* d_in, const int* in_sizes, int n_in,
                              void* d_out, int out_size, void* d_ws, size_t ws_size,
                              hipStream_t stream) {
  const float* grads     = (const float*)d_in[0];
  const int*   labels    = (const int*)d_in[1];
  const float* centroids = (const float*)d_in[2];
  float* out = (float*)d_out;
  char* ws = (char*)d_ws;

  float*    partial = (float*)(ws + OFF_PARTIAL);
  float*    NC      = (float*)(ws + OFF_NC);
  float*    MA      = (float*)(ws + OFF_MA);
  float*    MB      = (float*)(ws + OFF_MB);
  unsigned* counts  = (unsigned*)(ws + OFF_COUNTS);
  float*    colsum  = (float*)(ws + OFF_COLSUM);
  unsigned* maxbuf  = (unsigned*)(ws + OFF_MAXBUF);
  float*    v0      = (float*)(ws + OFF_V0);
  float*    y1      = (float*)(ws + OFF_Y1);
  float*    y2      = (float*)(ws + OFF_Y2);
  float*    vfin    = (float*)(ws + OFF_V);

  // zero the atomic targets (ws is poisoned once; re-zero every call)
  hipMemsetAsync(ws + OFF_ZERO, 0, ZERO_BYTES, stream);

  k_segsum<<<NGRP * NCHUNK, 512, NCLS * 33 * sizeof(float), stream>>>(grads, labels, partial);
  k_counts<<<64, 256, 0, stream>>>(labels, counts);
  k_reduce_ema<<<NCLS, 256, 0, stream>>>(partial, counts, centroids, NC);
  k_colsum<<<40, 256, 0, stream>>>(NC, colsum);
  k_gram<<<DIM, 256, 0, stream>>>(NC, colsum, MA, maxbuf);

  for (int t = 0; t < NSQ; ++t) {
    const float* A = (t & 1) ? MB : MA;
    float*       C = (t & 1) ? MA : MB;
    k_square<<<DIM, 256, 0, stream>>>(A, C, maxbuf + t, maxbuf + t + 1);
  }
  // NSQ even -> final matrix in MA
  k_pickcol<<<1, 256, 0, stream>>>(MA, v0);
  k_matvec<<<DIM, 256, 0, stream>>>(MA, v0, y1);
  k_matvec<<<DIM, 256, 0, stream>>>(MA, y1, y2);
  k_normalize<<<1, 256, 0, stream>>>(y2, vfin);

  k_project<<<2048, 256, 0, stream>>>((const float4*)grads, vfin, (float4*)out);
}

// Round 2
// 624.579 us; speedup vs baseline: 1.4409x; 1.4409x over previous
//
#include <hip/hip_runtime.h>

#define N_ROWS 400000
#define DIM 256
#define NCLS 1000
#define NSQ 10                        // matrix squarings -> G^(2^10)

// ---- workspace layout (bytes) ----
#define OFF_IDX     0                 // 400000 u32 = 1,600,000
#define OFF_ZERO    1600000           // zeroed region start
#define OFF_COUNTS  1600000           // 1024 u32
#define OFF_COLSUM  1604096           // 256 f32
#define OFF_MAXBUF  1605120           // 16 u32
#define ZERO_BYTES  (4096 + 1024 + 64)
#define OFF_BASE    1605184           // 1024 u32
#define OFF_CURSOR  1609280           // 1024 u32
#define OFF_V0      1613376
#define OFF_Y1      1614400
#define OFF_Y2      1615424
#define OFF_Y3      1616448
#define OFF_V       1617472
#define OFF_NC      1618496           // [NCLS][DIM] f32 = 1,024,000
#define OFF_MA      2642496           // 256KB
#define OFF_MB      2904640           // 256KB

// ---------- histogram of labels ----------
__global__ __launch_bounds__(256) void k_hist(const int* __restrict__ labels,
                                              unsigned* __restrict__ counts) {
  __shared__ unsigned c[NCLS];
  int t = threadIdx.x;
  for (int i = t; i < NCLS; i += 256) c[i] = 0u;
  __syncthreads();
  for (int i = blockIdx.x * 256 + t; i < N_ROWS; i += gridDim.x * 256)
    atomicAdd(&c[labels[i]], 1u);
  __syncthreads();
  for (int i = t; i < NCLS; i += 256) atomicAdd(&counts[i], c[i]);
}

// ---------- exclusive scan of counts -> base, cursor ----------
__global__ __launch_bounds__(1024) void k_scan(const unsigned* __restrict__ counts,
                                               unsigned* __restrict__ base,
                                               unsigned* __restrict__ cursor) {
  __shared__ unsigned s[1024];
  int t = threadIdx.x;
  unsigned v = (t < NCLS) ? counts[t] : 0u;
  s[t] = v;
  __syncthreads();
  for (int off = 1; off < 1024; off <<= 1) {
    unsigned add = (t >= off) ? s[t - off] : 0u;
    __syncthreads();
    s[t] += add;
    __syncthreads();
  }
  if (t < NCLS) {
    unsigned excl = s[t] - v;
    base[t] = excl;
    cursor[t] = excl;
  }
}

// ---------- scatter row indices into class-sorted order ----------
__global__ __launch_bounds__(256) void k_scatter(const int* __restrict__ labels,
                                                 unsigned* __restrict__ cursor,
                                                 unsigned* __restrict__ idx) {
  for (int i = blockIdx.x * 256 + threadIdx.x; i < N_ROWS; i += gridDim.x * 256) {
    unsigned p = atomicAdd(&cursor[labels[i]], 1u);
    idx[p] = (unsigned)i;
  }
}

// ---------- per-class gather-reduce + EMA -> NC ----------
__global__ __launch_bounds__(256) void k_reduce_ema(const float* __restrict__ grads,
                                                    const unsigned* __restrict__ idx,
                                                    const unsigned* __restrict__ base,
                                                    const unsigned* __restrict__ counts,
                                                    const float* __restrict__ centroids,
                                                    float* __restrict__ NC) {
  int cls = blockIdx.x;
  unsigned s0 = base[cls], n = counts[cls];
  int wave = threadIdx.x >> 6, lane = threadIdx.x & 63;
  const float4* g4 = (const float4*)grads;
  float4 acc = make_float4(0.f, 0.f, 0.f, 0.f);
  for (unsigned r = s0 + wave; r < s0 + n; r += 4) {
    unsigned row = idx[r];
    float4 v = g4[(size_t)row * 64 + lane];
    acc.x += v.x; acc.y += v.y; acc.z += v.z; acc.w += v.w;
  }
  __shared__ float4 tmp[4][64];
  tmp[wave][lane] = acc;
  __syncthreads();
  int d = threadIdx.x;
  const float* tf = (const float*)tmp;
  float ssum = tf[d] + tf[256 + d] + tf[512 + d] + tf[768 + d];
  float mean = ssum / fmaxf((float)n, 1.0f);
  float ce = centroids[cls * DIM + d];
  NC[cls * DIM + d] = (n > 0u) ? (0.9f * ce + 0.1f * mean) : ce;
}

// ---------- column sums of NC (for centering via G = NC'NC - s s'/C) ----------
__global__ __launch_bounds__(256) void k_colsum(const float* __restrict__ NC,
                                                float* __restrict__ colsum) {
  int t = threadIdx.x, b = blockIdx.x;   // 40 blocks x 25 classes
  float s = 0.0f;
  for (int cls = b * 25; cls < b * 25 + 25; ++cls) s += NC[cls * DIM + t];
  atomicAdd(&colsum[t], s);
}

// ---------- Gram of centered centroids + max|.| ----------
__global__ __launch_bounds__(256) void k_gram(const float* __restrict__ NC,
                                              const float* __restrict__ colsum,
                                              float* __restrict__ G,
                                              unsigned* __restrict__ maxb) {
  int j = blockIdx.x, i = threadIdx.x;
  float acc = 0.0f;
  #pragma unroll 4
  for (int k = 0; k < NCLS; ++k)
    acc += NC[k * DIM + i] * NC[k * DIM + j];   // i coalesced, j broadcast
  float val = acc - colsum[i] * colsum[j] * (1.0f / NCLS);
  G[j * DIM + i] = val;
  __shared__ float red[256];
  red[i] = fabsf(val);
  __syncthreads();
  for (int s = 128; s > 0; s >>= 1) {
    if (i < s) red[i] = fmaxf(red[i], red[i + s]);
    __syncthreads();
  }
  if (i == 0) atomicMax(maxb, __float_as_uint(red[0]));
}

// ---------- one normalized squaring step: C = (A/s)^2, track new max ----------
__global__ __launch_bounds__(256) void k_square(const float* __restrict__ A,
                                                float* __restrict__ C,
                                                const unsigned* __restrict__ maxb_in,
                                                unsigned* __restrict__ maxb_out) {
  int j = blockIdx.x, i = threadIdx.x;
  __shared__ float arow[DIM];
  arow[i] = A[j * DIM + i];                 // row j == column j (symmetric)
  __syncthreads();
  float inv = 1.0f / __uint_as_float(*maxb_in);
  float acc = 0.0f;
  #pragma unroll 8
  for (int k = 0; k < DIM; ++k)
    acc += A[k * DIM + i] * arow[k];
  float val = acc * inv * inv;
  C[j * DIM + i] = val;
  __shared__ float red[256];
  red[i] = fabsf(val);
  __syncthreads();
  for (int s = 128; s > 0; s >>= 1) {
    if (i < s) red[i] = fmaxf(red[i], red[i + s]);
    __syncthreads();
  }
  if (i == 0) atomicMax(maxb_out, __float_as_uint(red[0]));
}

// ---------- extract max-norm column of (near rank-1) M ----------
__global__ __launch_bounds__(256) void k_pickcol(const float* __restrict__ M,
                                                 float* __restrict__ v0) {
  int t = threadIdx.x;
  float ns = 0.0f;
  for (int k = 0; k < DIM; ++k) {
    float x = M[k * DIM + t];
    ns += x * x;
  }
  __shared__ float val[256];
  __shared__ int idx[256];
  val[t] = ns; idx[t] = t;
  __syncthreads();
  for (int s = 128; s > 0; s >>= 1) {
    if (t < s && val[t + s] > val[t]) { val[t] = val[t + s]; idx[t] = idx[t + s]; }
    __syncthreads();
  }
  int jm = idx[0];
  float nrm = sqrtf(fmaxf(val[0], 1e-30f));
  v0[t] = M[jm * DIM + t] / nrm;            // row jm == column jm (symmetric)
}

// ---------- matvec y = M x (256 blocks, one row each) ----------
__global__ __launch_bounds__(256) void k_matvec(const float* __restrict__ M,
                                                const float* __restrict__ x,
                                                float* __restrict__ y) {
  int j = blockIdx.x, t = threadIdx.x;
  __shared__ float red[256];
  red[t] = M[j * DIM + t] * x[t];
  __syncthreads();
  for (int s = 128; s > 0; s >>= 1) {
    if (t < s) red[t] += red[t + s];
    __syncthreads();
  }
  if (t == 0) y[j] = red[0];
}

// ---------- normalize ----------
__global__ __launch_bounds__(256) void k_normalize(const float* __restrict__ x,
                                                   float* __restrict__ v) {
  int t = threadIdx.x;
  float xv = x[t];
  __shared__ float red[256];
  red[t] = xv * xv;
  __syncthreads();
  for (int s = 128; s > 0; s >>= 1) {
    if (t < s) red[t] += red[t + s];
    __syncthreads();
  }
  v[t] = xv * rsqrtf(fmaxf(red[0], 1e-30f));
}

// ---------- pass 2: out = g - (g.v) v  (one wave per row, float4/lane) ----------
__global__ __launch_bounds__(256) void k_project(const float4* __restrict__ g4,
                                                 const float* __restrict__ v,
                                                 float4* __restrict__ out) {
  int lane = threadIdx.x & 63;
  float4 v4 = ((const float4*)v)[lane];
  int w = (blockIdx.x * 256 + threadIdx.x) >> 6;
  int nW = (gridDim.x * 256) >> 6;
  for (int r = w; r < N_ROWS; r += nW) {
    float4 g = g4[(size_t)r * 64 + lane];
    float d = g.x * v4.x + g.y * v4.y + g.z * v4.z + g.w * v4.w;
    #pragma unroll
    for (int m = 1; m < 64; m <<= 1) d += __shfl_xor(d, m, 64);
    float4 o = make_float4(g.x - d * v4.x, g.y - d * v4.y,
                           g.z - d * v4.z, g.w - d * v4.w);
    out[(size_t)r * 64 + lane] = o;
  }
}

extern "C" void kernel_launch(void* const* d_in, const int* in_sizes, int n_in,
                              void* d_out, int out_size, void* d_ws, size_t ws_size,
                              hipStream_t stream) {
  const float* grads     = (const float*)d_in[0];
  const int*   labels    = (const int*)d_in[1];
  const float* centroids = (const float*)d_in[2];
  float* out = (float*)d_out;
  char* ws = (char*)d_ws;

  unsigned* idx     = (unsigned*)(ws + OFF_IDX);
  unsigned* counts  = (unsigned*)(ws + OFF_COUNTS);
  float*    colsum  = (float*)(ws + OFF_COLSUM);
  unsigned* maxbuf  = (unsigned*)(ws + OFF_MAXBUF);
  unsigned* base    = (unsigned*)(ws + OFF_BASE);
  unsigned* cursor  = (unsigned*)(ws + OFF_CURSOR);
  float*    v0      = (float*)(ws + OFF_V0);
  float*    y1      = (float*)(ws + OFF_Y1);
  float*    y2      = (float*)(ws + OFF_Y2);
  float*    y3      = (float*)(ws + OFF_Y3);
  float*    vfin    = (float*)(ws + OFF_V);
  float*    NC      = (float*)(ws + OFF_NC);
  float*    MA      = (float*)(ws + OFF_MA);
  float*    MB      = (float*)(ws + OFF_MB);

  // zero the atomic targets (ws is poisoned once; re-zero every call)
  hipMemsetAsync(ws + OFF_ZERO, 0, ZERO_BYTES, stream);

  // counting sort of row indices by label
  k_hist<<<64, 256, 0, stream>>>(labels, counts);
  k_scan<<<1, 1024, 0, stream>>>(counts, base, cursor);
  k_scatter<<<256, 256, 0, stream>>>(labels, cursor, idx);

  // per-class mean + EMA
  k_reduce_ema<<<NCLS, 256, 0, stream>>>(grads, idx, base, counts, centroids, NC);

  // top eigenvector of centered Gram via repeated squaring + power polish
  k_colsum<<<40, 256, 0, stream>>>(NC, colsum);
  k_gram<<<DIM, 256, 0, stream>>>(NC, colsum, MA, maxbuf);
  for (int t = 0; t < NSQ; ++t) {
    const float* A = (t & 1) ? MB : MA;
    float*       C = (t & 1) ? MA : MB;
    k_square<<<DIM, 256, 0, stream>>>(A, C, maxbuf + t, maxbuf + t + 1);
  }
  // NSQ even -> final matrix in MA
  k_pickcol<<<1, 256, 0, stream>>>(MA, v0);
  k_matvec<<<DIM, 256, 0, stream>>>(MA, v0, y1);
  k_matvec<<<DIM, 256, 0, stream>>>(MA, y1, y2);
  k_matvec<<<DIM, 256, 0, stream>>>(MA, y2, y3);
  k_normalize<<<1, 256, 0, stream>>>(y3, vfin);

  // projection: out = g - (g.v) v
  k_project<<<2048, 256, 0, stream>>>((const float4*)grads, vfin, (float4*)out);
}